// Round 13
// baseline (147.032 us; speedup 1.0000x reference)
//
#include <hip/hip_runtime.h>

typedef float f32x4 __attribute__((ext_vector_type(4)));
typedef unsigned short u16x8 __attribute__((ext_vector_type(8)));
typedef __bf16 bf16x8 __attribute__((ext_vector_type(8)));
typedef __bf16 bf16x4 __attribute__((ext_vector_type(4)));

// ---------------------------------------------------------------------------
// Kernel 1: convert + transpose three W (fp32 [256 k][512 n]) into bf16 W^T
// [role][512 n][256 k] in workspace, via 64x64 LDS tile transpose.
// ---------------------------------------------------------------------------
__global__ __launch_bounds__(256) void convert_w_kernel(
    const float* __restrict__ Wt_, const float* __restrict__ Wi_,
    const float* __restrict__ Wo_, unsigned short* __restrict__ out)
{
    __shared__ unsigned short tile[64][72];

    const int b    = blockIdx.x;
    const int role = b >> 5;
    const int kt   = (b & 31) >> 3;
    const int nt   = b & 7;
    const float* __restrict__ W = (role == 0) ? Wt_ : ((role == 1) ? Wi_ : Wo_);

    const int t  = threadIdx.x;
    const int r0 = t >> 4;
    const int c4 = (t & 15) << 2;

#pragma unroll
    for (int j = 0; j < 4; ++j) {
        const int kl = r0 + j * 16;
        f32x4 v = *(const f32x4*)(W + (size_t)(kt * 64 + kl) * 512 + nt * 64 + c4);
#pragma unroll
        for (int e = 0; e < 4; ++e)
            tile[c4 + e][kl] = __builtin_bit_cast(unsigned short, (__bf16)v[e]);
    }
    __syncthreads();

    const int cs = t & 7;
#pragma unroll
    for (int p = 0; p < 2; ++p) {
        const int r = (t >> 3) + p * 32;
        u16x8 v = *(const u16x8*)&tile[r][cs * 8];
        *(u16x8*)(out + (size_t)role * 512 * 256 +
                  (size_t)(nt * 64 + r) * 256 + kt * 64 + cs * 8) = v;
    }
}

// ---------------------------------------------------------------------------
// Kernel 2: persistent counted-vmcnt pipeline (R10 components, zero full
// drains). Grid = 512 blocks (2/CU, one persistent round), 4 tiles each
// (role uniform: 4 | 32). Double-buffered 32 KB A tiles, NO separate
// scratch: each wave stages its OWN rows (8w..8w+7 = its private 4 KB of
// the buffer) so the epilogue can reuse the other buffer's same region as
// wave-private transpose scratch with same-wave in-order DS semantics.
// Per tile: compute buf[cur] -> issue next tile's cached A loads ->
// epilogue (scratch transpose + 16 NT full-line stores) -> convert+
// ds_write buf[cur^1] (compiler emits vmcnt(16): waits loads, stores stay
// in flight) -> raw s_barrier with lgkmcnt(0) ONLY. Reads, MFMA and store
// drain overlap continuously; __syncthreads' vmcnt(0) drain (the R1-R12
// phase-serializer) never happens inside the loop.
// ---------------------------------------------------------------------------
__global__ __launch_bounds__(512, 4) void role_proj_kernel(
    const float* __restrict__ A,            // [131072][256] fp32
    const int* __restrict__ tmask,          // [64]
    const int* __restrict__ imask,          // [64]
    const unsigned short* __restrict__ Wws, // [3][512][256] bf16 (W^T)
    const float* __restrict__ bt, const float* __restrict__ bi,
    const float* __restrict__ bo,
    float* __restrict__ C)                  // [131072][512] fp32
{
    __shared__ __align__(16) unsigned char smem[2][32 * 1024];

    const int tid  = threadIdx.x;
    const int lane = tid & 63;
    const int wid  = tid >> 6;              // 0..7
    const int t0   = blockIdx.x * 4;        // first tile

    // role uniform per block: mask index = tile/32 -> blockIdx/8
    const int mi   = blockIdx.x >> 3;
    const int role = tmask[mi] ? 0 : (imask[mi] ? 1 : 2);
    const unsigned short* __restrict__ W = Wws + (size_t)role * (512 * 256);
    const float* __restrict__ bias = (role == 0) ? bt : ((role == 1) ? bi : bo);

    const int l15   = lane & 15;
    const int l4    = lane >> 4;
    const int nbase = wid * 64;
    const int r7    = l15 & 7;
    const int srow  = wid * 8;              // wave-private staged rows

    const unsigned short* wp[4];
#pragma unroll
    for (int fn = 0; fn < 4; ++fn)
        wp[fn] = W + (size_t)(nbase + fn * 16 + l15) * 256 + l4 * 8;

    // ---- prologue: stage tile t0 into buf 0 (wave-private rows).
    // Load instr j: 64 lanes x consecutive 16 B = row (srow+j), full 1 KB.
    {
        const f32x4* ab = (const f32x4*)(A + (size_t)t0 * 16384) + srow * 64 + lane;
        f32x4 ld0[8];
#pragma unroll
        for (int j = 0; j < 8; ++j)
            ld0[j] = ab[j * 64];                       // cached (L3-resident)
#pragma unroll
        for (int j = 0; j < 8; ++j) {
            bf16x4 pk = { (__bf16)ld0[j][0], (__bf16)ld0[j][1],
                          (__bf16)ld0[j][2], (__bf16)ld0[j][3] };
            const int slot = (lane >> 1) ^ j;          // row&7 == j
            *(bf16x4*)(&smem[0][0] + (srow + j) * 512 + slot * 16 +
                       (lane & 1) * 8) = pk;
        }
    }
    asm volatile("s_waitcnt lgkmcnt(0)\n\ts_barrier" ::: "memory");

    int cur = 0;
#pragma unroll 1
    for (int t = 0; t < 4; ++t) {
        const unsigned short* As = (const unsigned short*)&smem[cur][0];

        // ---- compute tile t: wave = 64 rows x 64 cols
        f32x4 acc[4][4] = {};
#pragma unroll 1
        for (int ks = 0; ks < 8; ++ks) {
            u16x8 bfr[4];
#pragma unroll
            for (int fn = 0; fn < 4; ++fn)
                bfr[fn] = *(const u16x8*)(wp[fn] + ks * 32);   // L1/L2-hot
            u16x8 afr[4];
#pragma unroll
            for (int fm = 0; fm < 4; ++fm) {
                const int row  = fm * 16 + l15;
                const int slot = (ks * 4 + l4) ^ r7;
                afr[fm] = *(const u16x8*)&As[row * 256 + slot * 8];
            }
#pragma unroll
            for (int fm = 0; fm < 4; ++fm) {
#pragma unroll
                for (int fn = 0; fn < 4; ++fn) {
                    // swapped operands: acc row = out-channel (4 consecutive
                    // per lane via reg idx), col = activation row
                    acc[fm][fn] = __builtin_amdgcn_mfma_f32_16x16x32_bf16(
                        __builtin_bit_cast(bf16x8, bfr[fn]),
                        __builtin_bit_cast(bf16x8, afr[fm]),
                        acc[fm][fn], 0, 0, 0);
                }
            }
        }

        // ---- issue next tile's A loads FIRST (older than the NT stores, so
        // the later wait-for-loads is a counted vmcnt, not a drain)
        f32x4 ld[8];
        if (t < 3) {
            const f32x4* ab =
                (const f32x4*)(A + (size_t)(t0 + t + 1) * 16384) + srow * 64 + lane;
#pragma unroll
            for (int j = 0; j < 8; ++j)
                ld[j] = ab[j * 64];                    // cached (L3-resident)
        }

        // ---- epilogue: wave-private transpose scratch = my 4 KB region of
        // the OTHER buffer (free: last read one barrier ago; same-wave DS
        // ordering makes the later staging overwrite safe without a barrier).
        unsigned char* cs = &smem[cur ^ 1][0] + wid * 4096;
        f32x4 bv[4];
#pragma unroll
        for (int fn = 0; fn < 4; ++fn)
            bv[fn] = *(const f32x4*)(bias + nbase + fn * 16 + l4 * 4);

        const int m0 = (t0 + t) * 64;
#pragma unroll
        for (int fm = 0; fm < 4; ++fm) {
#pragma unroll
            for (int fn = 0; fn < 4; ++fn) {
                const int g = (fn * 4 + l4) ^ r7;
                *(f32x4*)(cs + l15 * 256 + g * 16) = acc[fm][fn] + bv[fn];
            }
#pragma unroll
            for (int q = 0; q < 4; ++q) {
                const int r = (lane >> 4) + 4 * q;     // act-row 0..15
                const int g = (lane & 15) ^ (r & 7);
                f32x4 v = *(const f32x4*)(cs + r * 256 + g * 16);
                __builtin_nontemporal_store(
                    v, (f32x4*)(C + (size_t)(m0 + fm * 16 + r) * 512 +
                                nbase + (lane & 15) * 4));
            }
        }

        // ---- stage next tile into my private region of buf[cur^1].
        // Compiler waits the A loads with a counted vmcnt (16 NT stores are
        // newer and stay outstanding across the barrier).
        if (t < 3) {
#pragma unroll
            for (int j = 0; j < 8; ++j) {
                bf16x4 pk = { (__bf16)ld[j][0], (__bf16)ld[j][1],
                              (__bf16)ld[j][2], (__bf16)ld[j][3] };
                const int slot = (lane >> 1) ^ j;
                *(bf16x4*)(&smem[cur ^ 1][0] + (srow + j) * 512 + slot * 16 +
                           (lane & 1) * 8) = pk;
            }
        }
        asm volatile("s_waitcnt lgkmcnt(0)\n\ts_barrier" ::: "memory");
        cur ^= 1;
    }
}

extern "C" void kernel_launch(void* const* d_in, const int* in_sizes, int n_in,
                              void* d_out, int out_size, void* d_ws, size_t ws_size,
                              hipStream_t stream) {
    const float* A   = (const float*)d_in[0];
    const int*   tm  = (const int*)d_in[1];
    const int*   im  = (const int*)d_in[2];
    const float* Wt_ = (const float*)d_in[3];
    const float* bt  = (const float*)d_in[4];
    const float* Wi_ = (const float*)d_in[5];
    const float* bi  = (const float*)d_in[6];
    const float* Wo_ = (const float*)d_in[7];
    const float* bo  = (const float*)d_in[8];

    unsigned short* Wws = (unsigned short*)d_ws;   // 3*512*256*2 = 768 KB

    hipLaunchKernelGGL(convert_w_kernel, dim3(96), dim3(256),
                       0, stream, Wt_, Wi_, Wo_, Wws);

    hipLaunchKernelGGL(role_proj_kernel, dim3(512), dim3(512),
                       0, stream, A, tm, im, Wws, bt, bi, bo, (float*)d_out);
}